// Round 7
// baseline (7058.899 us; speedup 1.0000x reference)
//
#include <hip/hip_runtime.h>
#include <stdint.h>

// Must match numpy float32 rounding exactly: (dx*dx + dy*dy) + dz*dz, no FMA.
#pragma clang fp contract(off)

#define NPT      2048
#define NBATCH   32
#define NPTS     65536
#define MEMBERS  8
#define NTHREADS 512
#define CHUNK    (NPTS / MEMBERS)       // 8192 points per block
#define PPT      (CHUNK / NTHREADS)     // 16 points per thread
#define WPB      (NTHREADS / 64)        // 8 waves per block
#define SLOTS    (MEMBERS * WPB)        // 64 wave-slots per batch (512B)

__device__ __forceinline__ uint32_t f2u(float f) { return __float_as_uint(f); }
__device__ __forceinline__ float u2f(uint32_t u) { return __uint_as_float(u); }

// argmax combine: larger value wins; tie -> smaller index (numpy argmax order)
__device__ __forceinline__ void amerge(float& v, int& i, float ov, int oi) {
    if (ov > v || (ov == v && oi < i)) { v = ov; i = oi; }
}

// DPP pairing round (VALU-speed) — verified absmax=0 in rounds 5/6
template<int CTRL>
__device__ __forceinline__ void dpp_round(float& v, int& i) {
    float ov = u2f((uint32_t)__builtin_amdgcn_mov_dpp((int)f2u(v), CTRL, 0xf, 0xf, true));
    int   oi = __builtin_amdgcn_mov_dpp(i, CTRL, 0xf, 0xf, true);
    amerge(v, i, ov, oi);
}
__device__ __forceinline__ void swz16_round(float& v, int& i) {   // lane ^ 16
    float ov = u2f((uint32_t)__builtin_amdgcn_ds_swizzle((int)f2u(v), 0x401F));
    int   oi = __builtin_amdgcn_ds_swizzle(i, 0x401F);
    amerge(v, i, ov, oi);
}
__device__ __forceinline__ void shfl32_round(float& v, int& i) {  // lane ^ 32
    float ov = __shfl_xor(v, 32, 64);
    int   oi = __shfl_xor(i, 32, 64);
    amerge(v, i, ov, oi);
}
// full 64-lane argmax: every lane ends with the global (max, min-index)
__device__ __forceinline__ void wave_argmax(float& v, int& i) {
    dpp_round<0xB1>(v, i);    // quad_perm xor1
    dpp_round<0x4E>(v, i);    // quad_perm xor2
    dpp_round<0x141>(v, i);   // row_half_mirror (merge 4-groups)
    dpp_round<0x140>(v, i);   // row_mirror      (merge 8-groups)
    swz16_round(v, i);        // xor16
    shfl32_round(v, i);       // xor32
}

__global__ void __launch_bounds__(NTHREADS)
fps_kernel(const float* __restrict__ xyz, int* __restrict__ out,
           uint64_t* __restrict__ cand)
{
    // x in LDS purely as register relief: each thread touches only its own
    // 16 slots (p = tid + k*512) -> no barriers, bank = tid%32 -> conflict-free.
    __shared__ float    sx[CHUNK];   // 32 KB
    __shared__ uint32_t bc[4];       // winner x,y,z broadcast

    // Swizzle: a batch's 8 member blocks share (blockIdx%32) -> same XCD under
    // round-robin dispatch (heuristic; correctness never depends on it).
    const int i = blockIdx.x;
    const int q = i >> 3;
    const int batch  = (i & 7) * 4 + (q & 3);   // [0,32)
    const int member = q >> 2;                  // [0,8)
    const int tid  = threadIdx.x;
    const int lane = tid & 63;
    const int wv   = tid >> 6;

    const float* xb = xyz + (size_t)batch * 3 * NPTS;
    const int gbase = member * CHUNK;

    float py[PPT], pz[PPT], pd[PPT];    // 48 data floats (R6: 48 VGPR, no spill)
#pragma unroll
    for (int k = 0; k < PPT; ++k) {
        int p = tid + k * NTHREADS;
        int g = gbase + p;
        sx[p] = xb[g];
        py[k] = xb[NPTS + g];
        pz[k] = xb[2 * NPTS + g];
        pd[k] = 1e10f;
    }

    // First centroid is point 0; first emitted index is 0.
    float cx = xb[0], cy = xb[NPTS], cz = xb[2 * NPTS];
    if (member == 0 && tid == 0) out[(size_t)batch * NPT] = 0;

    // cand[batch][parity][slot]: 64 x 8B = 512B contiguous per (batch,parity).
    uint64_t* cb = cand + (size_t)batch * 2 * SLOTS;
    const int sid = member * WPB + wv;          // this wave's slot [0,64)

    for (int t = 0; t < NPT - 1; ++t) {
        // ---- dist update + per-thread argmax (strict >, ascending k =
        //      ascending global index -> first-occurrence semantics) ----
        float bv = -1.0f;            // all dists >= 0, so always beaten
        int   bi = 0;
#pragma unroll
        for (int k = 0; k < PPT; ++k) {
            int p = tid + k * NTHREADS;
            float dx = sx[p] - cx;
            float dy = py[k] - cy;
            float dz = pz[k] - cz;
            float d  = dx * dx + dy * dy;   // contract(off): mul,mul,add
            d = d + dz * dz;                // then add — matches numpy order
            float nd = fminf(pd[k], d);
            pd[k] = nd;
            bool g = nd > bv;
            bv = g ? nd : bv;
            bi = g ? (gbase + p) : bi;
        }

        // ---- full wave argmax (DPP), then publish wave-best immediately ----
        wave_argmax(bv, bi);

        // ABA-safe tagging: a parity slot holding t is rewritten at t+2 only
        // after every block's wv0 completed poll(t+1), which (via the single
        // barrier) requires every block finished poll(t). Poison (0xAAAA) and
        // prior-replay tags (2046/2045) never match first polls (0/1) -> no
        // memset needed.
        uint64_t* sb = cb + (size_t)(t & 1) * SLOTS;
        const uint32_t tag = (uint32_t)t;
        if (lane == 0) {
            uint64_t w = ((uint64_t)f2u(bv) << 32)
                       | ((uint64_t)(uint32_t)bi << 16) | tag;
            __hip_atomic_store(&sb[sid], w, __ATOMIC_RELAXED,
                               __HIP_MEMORY_SCOPE_AGENT);
        }

        if (wv == 0) {
            __builtin_amdgcn_s_setprio(1);
            // ---- poll all 64 wave-slots: one slot per lane ----
            uint64_t w = 0; bool done = false;
            do {
                if (!done) w = __hip_atomic_load(&sb[lane], __ATOMIC_RELAXED,
                                                 __HIP_MEMORY_SCOPE_AGENT);
                done = (uint32_t)(w & 0xFFFFu) == tag;
            } while (!__all(done));

            // ---- global argmax across the 64 wave candidates ----
            float v  = u2f((uint32_t)(w >> 32));
            int   gi = (int)((w >> 16) & 0xFFFFu);
            wave_argmax(v, gi);

            // winner coords (uniform index, L2-resident) + output index
            if (lane < 3) bc[lane] = f2u(xb[(size_t)lane * NPTS + gi]);
            if (lane == 0 && member == 0) out[(size_t)batch * NPT + t + 1] = gi;
            __builtin_amdgcn_s_setprio(0);
        }
        __syncthreads();
        cx = u2f(bc[0]); cy = u2f(bc[1]); cz = u2f(bc[2]);
    }
}

extern "C" void kernel_launch(void* const* d_in, const int* in_sizes, int n_in,
                              void* d_out, int out_size, void* d_ws, size_t ws_size,
                              hipStream_t stream)
{
    const float* xyz = (const float*)d_in[0];
    int* out = (int*)d_out;
    uint64_t* cand = (uint64_t*)d_ws;   // 32*2*64*8 = 32 KiB used; no memset needed
    fps_kernel<<<NBATCH * MEMBERS, NTHREADS, 0, stream>>>(xyz, out, cand);
}